// Round 9
// baseline (200.342 us; speedup 1.0000x reference)
//
#include <hip/hip_runtime.h>
#include <hip/hip_bf16.h>
#include <math.h>

// PointCNN XConv dims (fixed)
#define NBATCH 32
#define NUMPT 2048
#define PP 1024
#define MPB 16                 // points per block in k_xconv
#define BN_INV 0.9999950000374996f

typedef __attribute__((ext_vector_type(8))) short short8;   // 8 bf16 (4 VGPRs)
typedef __attribute__((ext_vector_type(4))) short short4v;  // 4 bf16 (b64)
typedef __attribute__((ext_vector_type(4))) float f32x4;    // MFMA C/D

#define MFMA(a,b,c) __builtin_amdgcn_mfma_f32_16x16x32_bf16(a,b,c,0,0,0)

// ws layout (elements of short): fts_l bf16 [32][2048][64], then frag weights
#define FTSL_ELEMS 4194304
#define OFF_D0F  0           // unused by consumers now (GEMM blocks self-build)
#define OFF_XCF  4096        // [2kt][16nb][64][8]  K=64(48 valid) N=256
#define OFF_X1F  20480       // [8kt][16nb][64][8]  K=256 N=256
#define OFF_X2F  86016       // [8kt][16nb][64][8]
#define OFF_D2F  151552      // [1kt][2nb][64][8]   K=32  N=32
#define OFF_PWF  152576      // [6kt][8nb][64][8]   K=192 N=128

// k_setup prep-path source-linear region boundaries (gid starts at PB0)
#define PB0 4096      // (d0W region skipped - self-built by GEMM blocks)
#define PB1 16384     // xcW   (+256*48)
#define PB2 81920     // xd1W  (+256*256)
#define PB3 147456    // xd2W  (+256*256)
#define PB4 148480    // d2W   (+32*32)
#define PB5 173056    // pwW   (+192*128)
#define PB6 177152    // xcW pad zero-fill (+16*256)
#define NDB 512       // dense0 GEMM blocks in k_setup
#define NPREP 660     // (PB6-PB0)/256

// catF: c-major per point: [p][c 96][k 16], p-stride 1552 shorts (+8 banks)
#define CATP 1552

static __device__ __forceinline__ float eluf(float x) {
    return x > 0.0f ? x : (__expf(x) - 1.0f);
}
static __device__ __forceinline__ short f2bf(float x) {   // RNE fp32->bf16
    union { float f; unsigned u; } v; v.f = x;
    unsigned r = v.u + 0x7FFFu + ((v.u >> 16) & 1u);
    return (short)(r >> 16);
}
static __device__ __forceinline__ int f2bf2i(float a, float b) {  // packed RNE
    __hip_bfloat162 h = __float22bfloat162_rn(make_float2(a, b));
    int r; __builtin_memcpy(&r, &h, 4); return r;
}
union U8 { short8 s; int i[4]; };
union U4 { short4v s; int i[2]; };

// ---------------------------------------------------------------------------
// k_setup: blocks [0,NDB) = dense0 GEMM (fts -> fts_l bf16, self-built W0
// frags); blocks [NDB, NDB+NPREP) = weight->frag conversion (coalesced reads).
// ---------------------------------------------------------------------------
__global__ __launch_bounds__(256) void k_setup(
    const float* __restrict__ fts, const float* __restrict__ d0W,
    const float* __restrict__ xcW, const float* __restrict__ xd1W,
    const float* __restrict__ xd2W, const float* __restrict__ d2W,
    const float* __restrict__ pwW,
    const float* __restrict__ b, const float* __restrict__ g,
    const float* __restrict__ be,
    short* __restrict__ wf, short* __restrict__ fl)
{
    const int tid = threadIdx.x;
    if (blockIdx.x >= NDB) {
        // ---- prep path: one thread per source element, scattered 2B write ----
        const int gid = PB0 + (blockIdx.x - NDB) * 256 + tid;
        if (gid >= PB6) return;
        float val; int k, n, nt, off;
        if (gid < PB1) {            // xcW: K=48(of 64), N=256, NT=16; s=q*48+kk
            int s = gid - PB0;
            n = s / 48; k = s - n * 48; nt = 16; off = OFF_XCF;
            val = xcW[s];
        } else if (gid < PB2) {     // xd1W: K=256, N=256
            int s = gid - PB1;
            k = s >> 8; n = s & 255; nt = 16; off = OFF_X1F;
            val = xd1W[s];
        } else if (gid < PB3) {     // xd2W
            int s = gid - PB2;
            k = s >> 8; n = s & 255; nt = 16; off = OFF_X2F;
            val = xd2W[s];
        } else if (gid < PB4) {     // d2W: K=32, N=32
            int s = gid - PB3;
            k = s >> 5; n = s & 31; nt = 2; off = OFF_D2F;
            val = d2W[s];
        } else if (gid < PB5) {     // pwW: K=192, N=128
            int s = gid - PB4;
            k = s >> 7; n = s & 127; nt = 8; off = OFF_PWF;
            val = pwW[s];
        } else {                    // xcW pad: kk in [48,64), zero
            int s = gid - PB5;
            k = 48 + (s >> 8); n = s & 255; nt = 16; off = OFF_XCF;
            val = 0.0f;
        }
        const int dst = off + (((k >> 5) * nt + (n >> 4)) * 64
                               + ((k >> 3) & 3) * 16 + (n & 15)) * 8 + (k & 7);
        wf[dst] = f2bf(val);
        return;
    }

    // ---- dense0 GEMM path: D = W0^T (A, self-built) @ X^T (B) ----
    __shared__ __align__(16) short sB[2 * 4160];   // B-frags [kt2][nt8][65][8]
    __shared__ __align__(16) short sW0[4096];      // W0 A-frags [2kt][4mt][64][8]
    const long base = (long)blockIdx.x * 128 * 64;

    // self-build W0 frags: thread reads 16 consecutive d0W floats (1 k-row seg)
    {
        const int k = tid >> 2, n0 = (tid & 3) * 16;
        #pragma unroll
        for (int i4 = 0; i4 < 4; ++i4) {
            float4 v = *(const float4*)&d0W[k * 64 + n0 + i4 * 4];
            float vv[4] = {v.x, v.y, v.z, v.w};
            #pragma unroll
            for (int u = 0; u < 4; ++u) {
                int n = n0 + i4 * 4 + u;
                sW0[(((k >> 5) * 4 + (n >> 4)) * 64 + ((k >> 3) & 3) * 16 + (n & 15)) * 8 + (k & 7)]
                    = f2bf(vv[u]);
            }
        }
    }

    #pragma unroll
    for (int it = 0; it < 4; ++it) {
        const int gidx = tid + it * 256;          // 0..1023 = r*8 + o
        const int r = gidx >> 3, o = gidx & 7;    // row r (n dim), k-octet o
        float4 va = *(const float4*)&fts[base + r * 64 + o * 8];
        float4 vb = *(const float4*)&fts[base + r * 64 + o * 8 + 4];
        U8 pk;
        pk.i[0] = f2bf2i(va.x, va.y); pk.i[1] = f2bf2i(va.z, va.w);
        pk.i[2] = f2bf2i(vb.x, vb.y); pk.i[3] = f2bf2i(vb.z, vb.w);
        *(short8*)&sB[(o >> 2) * 4160 + (r >> 4) * 520 + ((o & 3) * 16 + (r & 15)) * 8] = pk.s;
    }
    __syncthreads();

    const int wave = tid >> 6, lane = tid & 63;
    const int col = lane & 15, quad = lane >> 4;
    const f32x4 fz = {0.f, 0.f, 0.f, 0.f};
    f32x4 acc[2][4] = {{fz, fz, fz, fz}, {fz, fz, fz, fz}};
    #pragma unroll
    for (int kt = 0; kt < 2; ++kt) {
        short8 af[4];
        #pragma unroll
        for (int mt = 0; mt < 4; ++mt)
            af[mt] = *(const short8*)&sW0[((kt * 4 + mt) * 64 + lane) * 8];
        #pragma unroll
        for (int ni = 0; ni < 2; ++ni) {
            short8 bf_ = *(const short8*)&sB[kt * 4160 + (wave * 2 + ni) * 520 + lane * 8];
            #pragma unroll
            for (int mt = 0; mt < 4; ++mt)
                acc[ni][mt] = MFMA(af[mt], bf_, acc[ni][mt]);
        }
    }
    // C/D: element (cout = mt*16 + quad*4 + r, row = (wave*2+ni)*16 + col)
    #pragma unroll
    for (int mt = 0; mt < 4; ++mt) {
        const int c0 = mt * 16 + quad * 4;
        float4 b4 = *(const float4*)&b[c0];
        float4 g4 = *(const float4*)&g[c0];
        float4 e4 = *(const float4*)&be[c0];
        g4.x *= BN_INV; g4.y *= BN_INV; g4.z *= BN_INV; g4.w *= BN_INV;
        #pragma unroll
        for (int ni = 0; ni < 2; ++ni) {
            long rowg = (long)blockIdx.x * 128 + (wave * 2 + ni) * 16 + col;
            U4 sv;
            sv.i[0] = f2bf2i(g4.x * eluf(acc[ni][mt][0] + b4.x) + e4.x,
                             g4.y * eluf(acc[ni][mt][1] + b4.y) + e4.y);
            sv.i[1] = f2bf2i(g4.z * eluf(acc[ni][mt][2] + b4.z) + e4.z,
                             g4.w * eluf(acc[ni][mt][3] + b4.w) + e4.w);
            *(short4v*)&fl[rowg * 64 + c0] = sv.s;
        }
    }
}

// ---------------------------------------------------------------------------
// Fused XConv: 16 points/block, 256 threads (4 waves), MFMA everywhere.
// ---------------------------------------------------------------------------
__global__ __launch_bounds__(256) void k_xconv(
    const float* __restrict__ rep_pts, const float* __restrict__ pts,
    const int* __restrict__ pts_idx, const short* __restrict__ fl,
    const short* __restrict__ wf,
    const float* __restrict__ d1W, const float* __restrict__ d1b,
    const float* __restrict__ d1g, const float* __restrict__ d1be,
    const float* __restrict__ d2b, const float* __restrict__ d2g,
    const float* __restrict__ d2be,
    const float* __restrict__ xcb, const float* __restrict__ xd1b,
    const float* __restrict__ xd2b,
    const float* __restrict__ dwW, const float* __restrict__ dwb,
    const float* __restrict__ pwb,
    const float* __restrict__ endg, const float* __restrict__ endbe,
    float* __restrict__ out)
{
    __shared__ __align__(16) short s_catF[MPB * CATP];  // [p][c96][k16], 48.5 KB
    __shared__ __align__(16) short s_big[8448];         // h1F [16][66][8] -> X1+X2
    __shared__ __align__(16) short s_X0b[4160];         // X0 A-frags [8kt][65][8] -> dwF
    __shared__ __align__(16) short s_plF[1024];         // pl A-frags, K=64 (48 valid)

    const int tid = threadIdx.x;
    const int wave = tid >> 6, lane = tid & 63;
    const int col = lane & 15, quad = lane >> 4;
    const int n = blockIdx.x >> 6;                  // 64 blocks per batch
    const int pb = (blockIdx.x & 63) * MPB;
    const long prow0 = (long)n * PP + pb;
    short* s_h1F = s_big;                           // [mt16][66 slots][8]
    short* s_X1 = s_big;                            // [kt8][65 slots][8] = 4160
    short* s_X2 = s_big + 4160;                     // [p16][264]
    short* s_dwF = s_X0b;                           // [nb6][64][8] = 3072
    const f32x4 fz = {0.f, 0.f, 0.f, 0.f};
    const short8 zz = {0, 0, 0, 0, 0, 0, 0, 0};

    // ---- S0: plF tail zero + idx + local coords (regs) ----
    for (int i = 768 + tid; i < 1024; i += 256) s_plF[i] = 0;
    const int p0 = tid >> 4, k0 = tid & 15;
    const int idxv = pts_idx[(prow0 + p0) * 16 + k0];
    float x0, x1, x2;
    {
        const float* pp = pts + ((long)n * NUMPT + idxv) * 3;
        const float* rp = rep_pts + (prow0 + p0) * 3;
        x0 = pp[0] - rp[0]; x1 = pp[1] - rp[1]; x2 = pp[2] - rp[2];
        const float v[3] = {x0, x1, x2};
        #pragma unroll
        for (int d = 0; d < 3; ++d) {
            int kk = d * 16 + k0;
            s_plF[((kk >> 5) * 64 + ((kk >> 3) & 3) * 16 + p0) * 8 + (kk & 7)] = f2bf(v[d]);
        }
    }

    // ---- E: issue gather loads early ----
    short8 gv[8];
    {
        const short8* gp = (const short8*)(fl + ((long)n * NUMPT + idxv) * 64);
        #pragma unroll
        for (int i = 0; i < 8; ++i) gv[i] = gp[i];
    }

    // ---- S1: d1 from registers -> h1F packed b128 writes ----
    #pragma unroll
    for (int oct = 0; oct < 4; ++oct) {
        U8 v8;
        float zv[8];
        #pragma unroll
        for (int u = 0; u < 8; ++u) {
            int c = oct * 8 + u;
            float z = d1b[c] + x0 * d1W[c] + x1 * d1W[32 + c] + x2 * d1W[64 + c];
            zv[u] = (d1g[c] * BN_INV) * eluf(z) + d1be[c];
        }
        v8.i[0] = f2bf2i(zv[0], zv[1]); v8.i[1] = f2bf2i(zv[2], zv[3]);
        v8.i[2] = f2bf2i(zv[4], zv[5]); v8.i[3] = f2bf2i(zv[6], zv[7]);
        *(short8*)&s_h1F[(p0 * 66 + oct * 16 + k0) * 8] = v8.s;
    }

    // ---- E2: gathered features -> catF c-major [p][c][k] ----
    {
        const int gbase = p0 * CATP + 32 * 16 + k0;   // c starts at 32
        #pragma unroll
        for (int i = 0; i < 8; ++i) {
            #pragma unroll
            for (int u = 0; u < 8; ++u)
                s_catF[gbase + (i * 8 + u) * 16] = gv[i][u];
        }
    }
    __syncthreads();

    // ---- D: h2 = dense2(h1) MFMA (M=256,K=32,N=32) -> catF c<32, b64 packed ----
    {
        const short8* B = (const short8*)(wf + OFF_D2F);
        short8 b0 = B[lane], b1 = B[64 + lane];
        short8 a[4];
        #pragma unroll
        for (int mt0 = 0; mt0 < 4; ++mt0)
            a[mt0] = *(const short8*)&s_h1F[((wave * 4 + mt0) * 66 + lane) * 8];
        #pragma unroll
        for (int nb = 0; nb < 2; ++nb) {
            int c2 = nb * 16 + col;
            float bb = d2b[c2], gg = d2g[c2] * BN_INV, bee = d2be[c2];
            #pragma unroll
            for (int mt0 = 0; mt0 < 4; ++mt0) {
                int mt = wave * 4 + mt0;             // == point p
                f32x4 acc = MFMA(a[mt0], nb ? b1 : b0, fz);
                U4 sv;
                sv.i[0] = f2bf2i(gg * eluf(acc[0] + bb) + bee,
                                 gg * eluf(acc[1] + bb) + bee);
                sv.i[1] = f2bf2i(gg * eluf(acc[2] + bb) + bee,
                                 gg * eluf(acc[3] + bb) + bee);
                *(short4v*)&s_catF[mt * CATP + c2 * 16 + quad * 4] = sv.s;
            }
        }
    }

    // ---- F: X0 = elu(pl-lift) (M=16,K=64(48),N=256) -> X0 A-frags ----
    {
        short8 a0 = *(const short8*)&s_plF[lane * 8];
        short8 a1 = *(const short8*)&s_plF[(64 + lane) * 8];
        const short8* B = (const short8*)(wf + OFF_XCF);
        #pragma unroll
        for (int t = 0; t < 4; ++t) {
            int nb = wave * 4 + t;
            f32x4 acc = MFMA(a0, B[nb * 64 + lane], fz);
            acc = MFMA(a1, B[(16 + nb) * 64 + lane], acc);
            int q = nb * 16 + col;
            float bq = xcb[q];
            #pragma unroll
            for (int r = 0; r < 4; ++r) {
                int p = quad * 4 + r;
                s_X0b[(q >> 5) * 520 + (((q >> 3) & 3) * 16 + p) * 8 + (q & 7)]
                    = f2bf(eluf(acc[r] + bq));
            }
        }
    }
    __syncthreads();

    // ---- G: X1 = elu(X0 @ xd1W + b) (M=16,K=256,N=256) ----
    {
        short8 a[8];
        #pragma unroll
        for (int kt = 0; kt < 8; ++kt)
            a[kt] = *(const short8*)&s_X0b[kt * 520 + lane * 8];
        const short8* B = (const short8*)(wf + OFF_X1F);
        #pragma unroll
        for (int t = 0; t < 4; ++t) {
            int nb = wave * 4 + t;
            f32x4 acc = fz;
            #pragma unroll
            for (int kt = 0; kt < 8; ++kt)
                acc = MFMA(a[kt], B[(kt * 16 + nb) * 64 + lane], acc);
            int q = nb * 16 + col;
            float bq = xd1b[q];
            #pragma unroll
            for (int r = 0; r < 4; ++r) {
                int p = quad * 4 + r;
                s_X1[(q >> 5) * 520 + (((q >> 3) & 3) * 16 + p) * 8 + (q & 7)]
                    = f2bf(eluf(acc[r] + bq));
            }
        }
    }
    __syncthreads();

    // ---- G2: X2 = X1 @ xd2W + b (no elu) -> per-point H A-layout ----
    {
        short8 a[8];
        #pragma unroll
        for (int kt = 0; kt < 8; ++kt)
            a[kt] = *(const short8*)&s_X1[kt * 520 + lane * 8];
        const short8* B = (const short8*)(wf + OFF_X2F);
        #pragma unroll
        for (int t = 0; t < 4; ++t) {
            int nb = wave * 4 + t;                   // == i (row of 16x16 X)
            f32x4 acc = fz;
            #pragma unroll
            for (int kt = 0; kt < 8; ++kt)
                acc = MFMA(a[kt], B[(kt * 16 + nb) * 64 + lane], acc);
            float bq = xd2b[nb * 16 + col];          // j = col
            #pragma unroll
            for (int r = 0; r < 4; ++r) {
                int p = quad * 4 + r;
                s_X2[p * 264 + ((col >> 3) * 16 + nb) * 8 + (col & 7)] = f2bf(acc[r] + bq);
            }
        }
    }
    __syncthreads();

    // ---- H: per-point fts_X = X2(16x16) @ cat(16x96), fused depthwise ----
    {
        float4 wd0[6], wd1[6]; float2 bdw[6];
        #pragma unroll
        for (int nb = 0; nb < 6; ++nb) {
            int c = nb * 16 + col;
            wd0[nb] = *(const float4*)&dwW[(c * 2 + 0) * 16 + quad * 4];
            wd1[nb] = *(const float4*)&dwW[(c * 2 + 1) * 16 + quad * 4];
            bdw[nb] = *(const float2*)&dwb[c * 2];
        }
        #pragma unroll
        for (int pi = 0; pi < 4; ++pi) {
            int p = wave * 4 + pi;
            short8 afr = zz;
            if (lane < 32) afr = *(const short8*)&s_X2[p * 264 + lane * 8];
            #pragma unroll
            for (int nb = 0; nb < 6; ++nb) {
                short8 bfr = zz;
                if (lane < 32)
                    bfr = *(const short8*)&s_catF[p * CATP + (nb * 16 + col) * 16 + quad * 8];
                f32x4 acc = MFMA(afr, bfr, fz);      // C row = i, col = c
                float q0 = acc[0] * wd0[nb].x + acc[1] * wd0[nb].y + acc[2] * wd0[nb].z + acc[3] * wd0[nb].w;
                float q1 = acc[0] * wd1[nb].x + acc[1] * wd1[nb].y + acc[2] * wd1[nb].z + acc[3] * wd1[nb].w;
                q0 += __shfl_xor(q0, 16); q0 += __shfl_xor(q0, 32);
                q1 += __shfl_xor(q1, 16); q1 += __shfl_xor(q1, 32);
                if (quad == 0) {
                    int c2 = col * 2;                // kk = nb*32 + c2 + dm
                    int ad = (nb * 64 + (c2 >> 3) * 16 + p) * 8 + (c2 & 7);
                    *(int*)&s_dwF[ad] = f2bf2i(q0 + bdw[nb].x, q1 + bdw[nb].y);
                }
            }
        }
    }
    __syncthreads();

    // ---- PW: out = BN(elu(dw @ pwW + b)) (M=16,K=192,N=128) ----
    {
        short8 a[6];
        #pragma unroll
        for (int kt = 0; kt < 6; ++kt)
            a[kt] = *(const short8*)&s_dwF[(kt * 64 + lane) * 8];
        const short8* B = (const short8*)(wf + OFF_PWF);
        #pragma unroll
        for (int t = 0; t < 2; ++t) {
            int nb = wave * 2 + t;
            f32x4 acc = fz;
            #pragma unroll
            for (int kt = 0; kt < 6; ++kt)
                acc = MFMA(a[kt], B[(kt * 8 + nb) * 64 + lane], acc);
            int o = nb * 16 + col;
            float bo = pwb[o], go = endg[o] * BN_INV, beo = endbe[o];
            #pragma unroll
            for (int r = 0; r < 4; ++r) {
                int p = quad * 4 + r;
                out[(prow0 + p) * 128 + o] = go * eluf(acc[r] + bo) + beo;
            }
        }
    }
}

extern "C" void kernel_launch(void* const* d_in, const int* in_sizes, int n_in,
                              void* d_out, int out_size, void* d_ws, size_t ws_size,
                              hipStream_t stream) {
    const float* rep_pts = (const float*)d_in[0];
    const float* pts     = (const float*)d_in[1];
    const float* fts     = (const float*)d_in[2];
    const int*   pts_idx = (const int*)d_in[3];
    const float* d0W = (const float*)d_in[4];
    const float* d0b = (const float*)d_in[5];
    const float* d0g = (const float*)d_in[6];
    const float* d0be = (const float*)d_in[7];
    const float* d1W = (const float*)d_in[8];
    const float* d1b = (const float*)d_in[9];
    const float* d1g = (const float*)d_in[10];
    const float* d1be = (const float*)d_in[11];
    const float* d2W = (const float*)d_in[12];
    const float* d2b = (const float*)d_in[13];
    const float* d2g = (const float*)d_in[14];
    const float* d2be = (const float*)d_in[15];
    const float* xcW = (const float*)d_in[16];
    const float* xcb = (const float*)d_in[17];
    const float* xd1W = (const float*)d_in[18];
    const float* xd1b = (const float*)d_in[19];
    const float* xd2W = (const float*)d_in[20];
    const float* xd2b = (const float*)d_in[21];
    const float* dwW = (const float*)d_in[22];
    const float* dwb = (const float*)d_in[23];
    const float* pwW = (const float*)d_in[24];
    const float* pwb = (const float*)d_in[25];
    const float* endg = (const float*)d_in[26];
    const float* endbe = (const float*)d_in[27];
    float* out = (float*)d_out;

    short* wsS = (short*)d_ws;
    short* fl = wsS;                    // fts_l bf16: 8.39 MB
    short* wf = wsS + FTSL_ELEMS;       // frag weights: 354 KB

    k_setup<<<NDB + NPREP, 256, 0, stream>>>(
        fts, d0W, xcW, xd1W, xd2W, d2W, pwW, d0b, d0g, d0be, wf, fl);
    k_xconv<<<NBATCH * (PP / MPB), 256, 0, stream>>>(
        rep_pts, pts, pts_idx, fl, wf,
        d1W, d1b, d1g, d1be, d2b, d2g, d2be,
        xcb, xd1b, xd2b, dwW, dwb, pwb, endg, endbe, out);
}

// Round 10
// 196.583 us; speedup vs baseline: 1.0191x; 1.0191x over previous
//
#include <hip/hip_runtime.h>
#include <hip/hip_bf16.h>
#include <math.h>

// PointCNN XConv dims (fixed)
#define NBATCH 32
#define NUMPT 2048
#define PP 1024
#define MPB 16                 // points per block in k_xconv
#define BN_INV 0.9999950000374996f

typedef __attribute__((ext_vector_type(8))) short short8;   // 8 bf16 (4 VGPRs)
typedef __attribute__((ext_vector_type(4))) short short4v;  // 4 bf16 (b64)
typedef __attribute__((ext_vector_type(4))) float f32x4;    // MFMA C/D

#define MFMA(a,b,c) __builtin_amdgcn_mfma_f32_16x16x32_bf16(a,b,c,0,0,0)

// ws layout (elements of short): fts_l bf16 [32][2048][64], then frag weights
#define FTSL_ELEMS 4194304
#define OFF_D0F  0           // unused by consumers now (GEMM blocks self-build)
#define OFF_XCF  4096        // [2kt][16nb][64][8]  K=64(48 valid) N=256
#define OFF_X1F  20480       // [8kt][16nb][64][8]  K=256 N=256
#define OFF_X2F  86016       // [8kt][16nb][64][8]
#define OFF_D2F  151552      // [1kt][2nb][64][8]   K=32  N=32
#define OFF_PWF  152576      // [6kt][8nb][64][8]   K=192 N=128

// k_setup prep-path source-linear region boundaries (gid starts at PB0)
#define PB0 4096      // (d0W region skipped - self-built by GEMM blocks)
#define PB1 16384     // xcW   (+256*48)
#define PB2 81920     // xd1W  (+256*256)
#define PB3 147456    // xd2W  (+256*256)
#define PB4 148480    // d2W   (+32*32)
#define PB5 173056    // pwW   (+192*128)
#define PB6 177152    // xcW pad zero-fill (+16*256)
#define NDB 512       // dense0 GEMM blocks in k_setup
#define NPREP 660     // (PB6-PB0)/256

// catF: c-major per point: [p][c 96][k 16], p-stride 1552 shorts (+8 banks)
#define CATP 1552

static __device__ __forceinline__ float eluf(float x) {
    return x > 0.0f ? x : (__expf(x) - 1.0f);
}
static __device__ __forceinline__ short f2bf(float x) {   // RNE fp32->bf16
    union { float f; unsigned u; } v; v.f = x;
    unsigned r = v.u + 0x7FFFu + ((v.u >> 16) & 1u);
    return (short)(r >> 16);
}
static __device__ __forceinline__ int f2bf2i(float a, float b) {  // packed RNE
    __hip_bfloat162 h = __float22bfloat162_rn(make_float2(a, b));
    int r; __builtin_memcpy(&r, &h, 4); return r;
}
union U8 { short8 s; int i[4]; };
union U4 { short4v s; int i[2]; };

// ---------------------------------------------------------------------------
// k_setup: blocks [0,NDB) = dense0 GEMM (fts -> fts_l bf16, self-built W0
// frags); blocks [NDB, NDB+NPREP) = weight->frag conversion (coalesced reads).
// ---------------------------------------------------------------------------
__global__ __launch_bounds__(256) void k_setup(
    const float* __restrict__ fts, const float* __restrict__ d0W,
    const float* __restrict__ xcW, const float* __restrict__ xd1W,
    const float* __restrict__ xd2W, const float* __restrict__ d2W,
    const float* __restrict__ pwW,
    const float* __restrict__ b, const float* __restrict__ g,
    const float* __restrict__ be,
    short* __restrict__ wf, short* __restrict__ fl)
{
    const int tid = threadIdx.x;
    if (blockIdx.x >= NDB) {
        // ---- prep path: one thread per source element, scattered 2B write ----
        const int gid = PB0 + (blockIdx.x - NDB) * 256 + tid;
        if (gid >= PB6) return;
        float val; int k, n, nt, off;
        if (gid < PB1) {            // xcW: K=48(of 64), N=256, NT=16; s=q*48+kk
            int s = gid - PB0;
            n = s / 48; k = s - n * 48; nt = 16; off = OFF_XCF;
            val = xcW[s];
        } else if (gid < PB2) {     // xd1W: K=256, N=256
            int s = gid - PB1;
            k = s >> 8; n = s & 255; nt = 16; off = OFF_X1F;
            val = xd1W[s];
        } else if (gid < PB3) {     // xd2W
            int s = gid - PB2;
            k = s >> 8; n = s & 255; nt = 16; off = OFF_X2F;
            val = xd2W[s];
        } else if (gid < PB4) {     // d2W: K=32, N=32
            int s = gid - PB3;
            k = s >> 5; n = s & 31; nt = 2; off = OFF_D2F;
            val = d2W[s];
        } else if (gid < PB5) {     // pwW: K=192, N=128
            int s = gid - PB4;
            k = s >> 7; n = s & 127; nt = 8; off = OFF_PWF;
            val = pwW[s];
        } else {                    // xcW pad: kk in [48,64), zero
            int s = gid - PB5;
            k = 48 + (s >> 8); n = s & 255; nt = 16; off = OFF_XCF;
            val = 0.0f;
        }
        const int dst = off + (((k >> 5) * nt + (n >> 4)) * 64
                               + ((k >> 3) & 3) * 16 + (n & 15)) * 8 + (k & 7);
        wf[dst] = f2bf(val);
        return;
    }

    // ---- dense0 GEMM path: D = W0^T (A, self-built) @ X^T (B) ----
    __shared__ __align__(16) short sB[2 * 4160];   // B-frags [kt2][nt8][65][8]
    __shared__ __align__(16) short sW0[4096];      // W0 A-frags [2kt][4mt][64][8]
    const long base = (long)blockIdx.x * 128 * 64;

    // self-build W0 frags: thread reads 16 consecutive d0W floats (1 k-row seg)
    {
        const int k = tid >> 2, n0 = (tid & 3) * 16;
        #pragma unroll
        for (int i4 = 0; i4 < 4; ++i4) {
            float4 v = *(const float4*)&d0W[k * 64 + n0 + i4 * 4];
            float vv[4] = {v.x, v.y, v.z, v.w};
            #pragma unroll
            for (int u = 0; u < 4; ++u) {
                int n = n0 + i4 * 4 + u;
                sW0[(((k >> 5) * 4 + (n >> 4)) * 64 + ((k >> 3) & 3) * 16 + (n & 15)) * 8 + (k & 7)]
                    = f2bf(vv[u]);
            }
        }
    }

    #pragma unroll
    for (int it = 0; it < 4; ++it) {
        const int gidx = tid + it * 256;          // 0..1023 = r*8 + o
        const int r = gidx >> 3, o = gidx & 7;    // row r (n dim), k-octet o
        float4 va = *(const float4*)&fts[base + r * 64 + o * 8];
        float4 vb = *(const float4*)&fts[base + r * 64 + o * 8 + 4];
        U8 pk;
        pk.i[0] = f2bf2i(va.x, va.y); pk.i[1] = f2bf2i(va.z, va.w);
        pk.i[2] = f2bf2i(vb.x, vb.y); pk.i[3] = f2bf2i(vb.z, vb.w);
        *(short8*)&sB[(o >> 2) * 4160 + (r >> 4) * 520 + ((o & 3) * 16 + (r & 15)) * 8] = pk.s;
    }
    __syncthreads();

    const int wave = tid >> 6, lane = tid & 63;
    const int col = lane & 15, quad = lane >> 4;
    const f32x4 fz = {0.f, 0.f, 0.f, 0.f};
    f32x4 acc[2][4] = {{fz, fz, fz, fz}, {fz, fz, fz, fz}};
    #pragma unroll
    for (int kt = 0; kt < 2; ++kt) {
        short8 af[4];
        #pragma unroll
        for (int mt = 0; mt < 4; ++mt)
            af[mt] = *(const short8*)&sW0[((kt * 4 + mt) * 64 + lane) * 8];
        #pragma unroll
        for (int ni = 0; ni < 2; ++ni) {
            short8 bf_ = *(const short8*)&sB[kt * 4160 + (wave * 2 + ni) * 520 + lane * 8];
            #pragma unroll
            for (int mt = 0; mt < 4; ++mt)
                acc[ni][mt] = MFMA(af[mt], bf_, acc[ni][mt]);
        }
    }
    // C/D: element (cout = mt*16 + quad*4 + r, row = (wave*2+ni)*16 + col)
    #pragma unroll
    for (int mt = 0; mt < 4; ++mt) {
        const int c0 = mt * 16 + quad * 4;
        float4 b4 = *(const float4*)&b[c0];
        float4 g4 = *(const float4*)&g[c0];
        float4 e4 = *(const float4*)&be[c0];
        g4.x *= BN_INV; g4.y *= BN_INV; g4.z *= BN_INV; g4.w *= BN_INV;
        #pragma unroll
        for (int ni = 0; ni < 2; ++ni) {
            long rowg = (long)blockIdx.x * 128 + (wave * 2 + ni) * 16 + col;
            U4 sv;
            sv.i[0] = f2bf2i(g4.x * eluf(acc[ni][mt][0] + b4.x) + e4.x,
                             g4.y * eluf(acc[ni][mt][1] + b4.y) + e4.y);
            sv.i[1] = f2bf2i(g4.z * eluf(acc[ni][mt][2] + b4.z) + e4.z,
                             g4.w * eluf(acc[ni][mt][3] + b4.w) + e4.w);
            *(short4v*)&fl[rowg * 64 + c0] = sv.s;
        }
    }
}

// ---------------------------------------------------------------------------
// Fused XConv: 16 points/block, 256 threads (4 waves), MFMA everywhere.
// Weight streams software-pipelined across barriers (loads are pure-global,
// hoisted above __syncthreads which the compiler's fence semantics forbid).
// ---------------------------------------------------------------------------
__global__ __launch_bounds__(256) void k_xconv(
    const float* __restrict__ rep_pts, const float* __restrict__ pts,
    const int* __restrict__ pts_idx, const short* __restrict__ fl,
    const short* __restrict__ wf,
    const float* __restrict__ d1W, const float* __restrict__ d1b,
    const float* __restrict__ d1g, const float* __restrict__ d1be,
    const float* __restrict__ d2b, const float* __restrict__ d2g,
    const float* __restrict__ d2be,
    const float* __restrict__ xcb, const float* __restrict__ xd1b,
    const float* __restrict__ xd2b,
    const float* __restrict__ dwW, const float* __restrict__ dwb,
    const float* __restrict__ pwb,
    const float* __restrict__ endg, const float* __restrict__ endbe,
    float* __restrict__ out)
{
    __shared__ __align__(16) short s_catF[MPB * CATP];  // [p][c96][k16], 48.5 KB
    __shared__ __align__(16) short s_big[8448];         // h1F [16][66][8] -> X1+X2
    __shared__ __align__(16) short s_X0b[4160];         // X0 A-frags [8kt][65][8] -> dwF
    __shared__ __align__(16) short s_plF[1024];         // pl A-frags, K=64 (48 valid)

    const int tid = threadIdx.x;
    const int wave = tid >> 6, lane = tid & 63;
    const int col = lane & 15, quad = lane >> 4;
    const int n = blockIdx.x >> 6;                  // 64 blocks per batch
    const int pb = (blockIdx.x & 63) * MPB;
    const long prow0 = (long)n * PP + pb;
    short* s_h1F = s_big;                           // [mt16][66 slots][8]
    short* s_X1 = s_big;                            // [kt8][65 slots][8] = 4160
    short* s_X2 = s_big + 4160;                     // [p16][264]
    short* s_dwF = s_X0b;                           // [nb6][64][8] = 3072
    const f32x4 fz = {0.f, 0.f, 0.f, 0.f};
    const short8 zz = {0, 0, 0, 0, 0, 0, 0, 0};

    // ---- S0: plF tail zero + idx + local coords (regs) ----
    for (int i = 768 + tid; i < 1024; i += 256) s_plF[i] = 0;
    const int p0 = tid >> 4, k0 = tid & 15;
    const int idxv = pts_idx[(prow0 + p0) * 16 + k0];
    float x0, x1, x2;
    {
        const float* pp = pts + ((long)n * NUMPT + idxv) * 3;
        const float* rp = rep_pts + (prow0 + p0) * 3;
        x0 = pp[0] - rp[0]; x1 = pp[1] - rp[1]; x2 = pp[2] - rp[2];
        const float v[3] = {x0, x1, x2};
        #pragma unroll
        for (int d = 0; d < 3; ++d) {
            int kk = d * 16 + k0;
            s_plF[((kk >> 5) * 64 + ((kk >> 3) & 3) * 16 + p0) * 8 + (kk & 7)] = f2bf(v[d]);
        }
    }

    // ---- E: issue gather loads early ----
    short8 gv[8];
    {
        const short8* gp = (const short8*)(fl + ((long)n * NUMPT + idxv) * 64);
        #pragma unroll
        for (int i = 0; i < 8; ++i) gv[i] = gp[i];
    }

    // ---- prefetch F's B-frags + D's B-frags (global, barrier-independent) ----
    short8 wfF[8];
    {
        const short8* B = (const short8*)(wf + OFF_XCF);
        #pragma unroll
        for (int t = 0; t < 4; ++t) {
            wfF[t]     = B[(wave * 4 + t) * 64 + lane];
            wfF[4 + t] = B[(16 + wave * 4 + t) * 64 + lane];
        }
    }
    short8 wfD0, wfD1;
    {
        const short8* B = (const short8*)(wf + OFF_D2F);
        wfD0 = B[lane]; wfD1 = B[64 + lane];
    }

    // ---- S1: d1 from registers -> h1F packed b128 writes ----
    #pragma unroll
    for (int oct = 0; oct < 4; ++oct) {
        U8 v8;
        float zv[8];
        #pragma unroll
        for (int u = 0; u < 8; ++u) {
            int c = oct * 8 + u;
            float z = d1b[c] + x0 * d1W[c] + x1 * d1W[32 + c] + x2 * d1W[64 + c];
            zv[u] = (d1g[c] * BN_INV) * eluf(z) + d1be[c];
        }
        v8.i[0] = f2bf2i(zv[0], zv[1]); v8.i[1] = f2bf2i(zv[2], zv[3]);
        v8.i[2] = f2bf2i(zv[4], zv[5]); v8.i[3] = f2bf2i(zv[6], zv[7]);
        *(short8*)&s_h1F[(p0 * 66 + oct * 16 + k0) * 8] = v8.s;
    }

    // ---- E2: gathered features -> catF c-major [p][c][k] ----
    {
        const int gbase = p0 * CATP + 32 * 16 + k0;   // c starts at 32
        #pragma unroll
        for (int i = 0; i < 8; ++i) {
            #pragma unroll
            for (int u = 0; u < 8; ++u)
                s_catF[gbase + (i * 8 + u) * 16] = gv[i][u];
        }
    }
    __syncthreads();

    // ---- F: X0 = elu(pl-lift) (M=16,K=64(48),N=256) -> X0 A-frags ----
    {
        short8 a0 = *(const short8*)&s_plF[lane * 8];
        short8 a1 = *(const short8*)&s_plF[(64 + lane) * 8];
        #pragma unroll
        for (int t = 0; t < 4; ++t) {
            int nb = wave * 4 + t;
            f32x4 acc = MFMA(a0, wfF[t], fz);
            acc = MFMA(a1, wfF[4 + t], acc);
            int q = nb * 16 + col;
            float bq = xcb[q];
            #pragma unroll
            for (int r = 0; r < 4; ++r) {
                int p = quad * 4 + r;
                s_X0b[(q >> 5) * 520 + (((q >> 3) & 3) * 16 + p) * 8 + (q & 7)]
                    = f2bf(eluf(acc[r] + bq));
            }
        }
    }

    // ---- D: h2 = dense2(h1) MFMA (M=256,K=32,N=32) -> catF c<32, b64 packed ----
    {
        short8 a[4];
        #pragma unroll
        for (int mt0 = 0; mt0 < 4; ++mt0)
            a[mt0] = *(const short8*)&s_h1F[((wave * 4 + mt0) * 66 + lane) * 8];
        #pragma unroll
        for (int nb = 0; nb < 2; ++nb) {
            int c2 = nb * 16 + col;
            float bb = d2b[c2], gg = d2g[c2] * BN_INV, bee = d2be[c2];
            #pragma unroll
            for (int mt0 = 0; mt0 < 4; ++mt0) {
                int mt = wave * 4 + mt0;             // == point p
                f32x4 acc = MFMA(a[mt0], nb ? wfD1 : wfD0, fz);
                U4 sv;
                sv.i[0] = f2bf2i(gg * eluf(acc[0] + bb) + bee,
                                 gg * eluf(acc[1] + bb) + bee);
                sv.i[1] = f2bf2i(gg * eluf(acc[2] + bb) + bee,
                                 gg * eluf(acc[3] + bb) + bee);
                *(short4v*)&s_catF[mt * CATP + c2 * 16 + quad * 4] = sv.s;
            }
        }
    }

    // ---- prefetch G's first-half B-frags (kt 0..3) before the barrier ----
    short8 wg[16];
    {
        const short8* B = (const short8*)(wf + OFF_X1F);
        #pragma unroll
        for (int kt = 0; kt < 4; ++kt)
            #pragma unroll
            for (int t = 0; t < 4; ++t)
                wg[kt * 4 + t] = B[(kt * 16 + wave * 4 + t) * 64 + lane];
    }
    __syncthreads();

    // ---- G: X1 = elu(X0 @ xd1W + b) (M=16,K=256,N=256) ----
    {
        short8 a[8];
        #pragma unroll
        for (int kt = 0; kt < 8; ++kt)
            a[kt] = *(const short8*)&s_X0b[kt * 520 + lane * 8];
        const short8* B = (const short8*)(wf + OFF_X1F);
        #pragma unroll
        for (int t = 0; t < 4; ++t) {
            int nb = wave * 4 + t;
            f32x4 acc = fz;
            #pragma unroll
            for (int kt = 0; kt < 4; ++kt)
                acc = MFMA(a[kt], wg[kt * 4 + t], acc);
            #pragma unroll
            for (int kt = 4; kt < 8; ++kt)
                acc = MFMA(a[kt], B[(kt * 16 + nb) * 64 + lane], acc);
            int q = nb * 16 + col;
            float bq = xd1b[q];
            #pragma unroll
            for (int r = 0; r < 4; ++r) {
                int p = quad * 4 + r;
                s_X1[(q >> 5) * 520 + (((q >> 3) & 3) * 16 + p) * 8 + (q & 7)]
                    = f2bf(eluf(acc[r] + bq));
            }
        }
    }
    // ---- prefetch G2's first-half B-frags before the barrier ----
    {
        const short8* B = (const short8*)(wf + OFF_X2F);
        #pragma unroll
        for (int kt = 0; kt < 4; ++kt)
            #pragma unroll
            for (int t = 0; t < 4; ++t)
                wg[kt * 4 + t] = B[(kt * 16 + wave * 4 + t) * 64 + lane];
    }
    __syncthreads();

    // ---- G2: X2 = X1 @ xd2W + b (no elu) -> per-point H A-layout ----
    {
        short8 a[8];
        #pragma unroll
        for (int kt = 0; kt < 8; ++kt)
            a[kt] = *(const short8*)&s_X1[kt * 520 + lane * 8];
        const short8* B = (const short8*)(wf + OFF_X2F);
        #pragma unroll
        for (int t = 0; t < 4; ++t) {
            int nb = wave * 4 + t;                   // == i (row of 16x16 X)
            f32x4 acc = fz;
            #pragma unroll
            for (int kt = 0; kt < 4; ++kt)
                acc = MFMA(a[kt], wg[kt * 4 + t], acc);
            #pragma unroll
            for (int kt = 4; kt < 8; ++kt)
                acc = MFMA(a[kt], B[(kt * 16 + nb) * 64 + lane], acc);
            float bq = xd2b[nb * 16 + col];          // j = col
            #pragma unroll
            for (int r = 0; r < 4; ++r) {
                int p = quad * 4 + r;
                s_X2[p * 264 + ((col >> 3) * 16 + nb) * 8 + (col & 7)] = f2bf(acc[r] + bq);
            }
        }
    }
    // ---- prefetch H's depthwise consts before the barrier ----
    float4 wd0[6], wd1[6]; float2 bdw[6];
    #pragma unroll
    for (int nb = 0; nb < 6; ++nb) {
        int c = nb * 16 + col;
        wd0[nb] = *(const float4*)&dwW[(c * 2 + 0) * 16 + quad * 4];
        wd1[nb] = *(const float4*)&dwW[(c * 2 + 1) * 16 + quad * 4];
        bdw[nb] = *(const float2*)&dwb[c * 2];
    }
    __syncthreads();

    // ---- H: per-point fts_X = X2(16x16) @ cat(16x96), fused depthwise ----
    {
        #pragma unroll
        for (int pi = 0; pi < 4; ++pi) {
            int p = wave * 4 + pi;
            short8 afr = zz;
            if (lane < 32) afr = *(const short8*)&s_X2[p * 264 + lane * 8];
            #pragma unroll
            for (int nb = 0; nb < 6; ++nb) {
                short8 bfr = zz;
                if (lane < 32)
                    bfr = *(const short8*)&s_catF[p * CATP + (nb * 16 + col) * 16 + quad * 8];
                f32x4 acc = MFMA(afr, bfr, fz);      // C row = i, col = c
                float q0 = acc[0] * wd0[nb].x + acc[1] * wd0[nb].y + acc[2] * wd0[nb].z + acc[3] * wd0[nb].w;
                float q1 = acc[0] * wd1[nb].x + acc[1] * wd1[nb].y + acc[2] * wd1[nb].z + acc[3] * wd1[nb].w;
                q0 += __shfl_xor(q0, 16); q0 += __shfl_xor(q0, 32);
                q1 += __shfl_xor(q1, 16); q1 += __shfl_xor(q1, 32);
                if (quad == 0) {
                    int c2 = col * 2;                // kk = nb*32 + c2 + dm
                    int ad = (nb * 64 + (c2 >> 3) * 16 + p) * 8 + (c2 & 7);
                    *(int*)&s_dwF[ad] = f2bf2i(q0 + bdw[nb].x, q1 + bdw[nb].y);
                }
            }
        }
    }
    // ---- prefetch PW's B-frags before the barrier ----
    short8 wp[12];
    {
        const short8* B = (const short8*)(wf + OFF_PWF);
        #pragma unroll
        for (int kt = 0; kt < 6; ++kt)
            #pragma unroll
            for (int t = 0; t < 2; ++t)
                wp[kt * 2 + t] = B[(kt * 8 + wave * 2 + t) * 64 + lane];
    }
    __syncthreads();

    // ---- PW: out = BN(elu(dw @ pwW + b)) (M=16,K=192,N=128) ----
    {
        short8 a[6];
        #pragma unroll
        for (int kt = 0; kt < 6; ++kt)
            a[kt] = *(const short8*)&s_dwF[(kt * 64 + lane) * 8];
        #pragma unroll
        for (int t = 0; t < 2; ++t) {
            int nb = wave * 2 + t;
            f32x4 acc = fz;
            #pragma unroll
            for (int kt = 0; kt < 6; ++kt)
                acc = MFMA(a[kt], wp[kt * 2 + t], acc);
            int o = nb * 16 + col;
            float bo = pwb[o], go = endg[o] * BN_INV, beo = endbe[o];
            #pragma unroll
            for (int r = 0; r < 4; ++r) {
                int p = quad * 4 + r;
                out[(prow0 + p) * 128 + o] = go * eluf(acc[r] + bo) + beo;
            }
        }
    }
}

extern "C" void kernel_launch(void* const* d_in, const int* in_sizes, int n_in,
                              void* d_out, int out_size, void* d_ws, size_t ws_size,
                              hipStream_t stream) {
    const float* rep_pts = (const float*)d_in[0];
    const float* pts     = (const float*)d_in[1];
    const float* fts     = (const float*)d_in[2];
    const int*   pts_idx = (const int*)d_in[3];
    const float* d0W = (const float*)d_in[4];
    const float* d0b = (const float*)d_in[5];
    const float* d0g = (const float*)d_in[6];
    const float* d0be = (const float*)d_in[7];
    const float* d1W = (const float*)d_in[8];
    const float* d1b = (const float*)d_in[9];
    const float* d1g = (const float*)d_in[10];
    const float* d1be = (const float*)d_in[11];
    const float* d2W = (const float*)d_in[12];
    const float* d2b = (const float*)d_in[13];
    const float* d2g = (const float*)d_in[14];
    const float* d2be = (const float*)d_in[15];
    const float* xcW = (const float*)d_in[16];
    const float* xcb = (const float*)d_in[17];
    const float* xd1W = (const float*)d_in[18];
    const float* xd1b = (const float*)d_in[19];
    const float* xd2W = (const float*)d_in[20];
    const float* xd2b = (const float*)d_in[21];
    const float* dwW = (const float*)d_in[22];
    const float* dwb = (const float*)d_in[23];
    const float* pwW = (const float*)d_in[24];
    const float* pwb = (const float*)d_in[25];
    const float* endg = (const float*)d_in[26];
    const float* endbe = (const float*)d_in[27];
    float* out = (float*)d_out;

    short* wsS = (short*)d_ws;
    short* fl = wsS;                    // fts_l bf16: 8.39 MB
    short* wf = wsS + FTSL_ELEMS;       // frag weights: 354 KB

    k_setup<<<NDB + NPREP, 256, 0, stream>>>(
        fts, d0W, xcW, xd1W, xd2W, d2W, pwW, d0b, d0g, d0be, wf, fl);
    k_xconv<<<NBATCH * (PP / MPB), 256, 0, stream>>>(
        rep_pts, pts, pts_idx, fl, wf,
        d1W, d1b, d1g, d1be, d2b, d2g, d2be,
        xcb, xd1b, xd2b, dwW, dwb, pwb, endg, endbe, out);
}